// Round 5
// baseline (795.070 us; speedup 1.0000x reference)
//
#include <hip/hip_runtime.h>
#include <stdint.h>

// SimpleTrixFFN round 5: ring-4 x BK=32 pipelined 256x256 GEMM.
// Gating = round-3-proven counted vmcnt(8) BEFORE any ds_read of the unit
// (round 4's race: reads issued before the gate). Compute = two 16-MFMA
// phases per unit with lgkmcnt(0)+sched_barrier+setprio (T3+T4+T5), T2 swizzle.

typedef __attribute__((ext_vector_type(8))) __bf16 bf16x8;
typedef __attribute__((ext_vector_type(4))) float f32x4;

__device__ __forceinline__ unsigned short f2bf(float f) {
  union { float f; unsigned int u; } c; c.f = f;
  unsigned int u = c.u;
  u += 0x7FFFu + ((u >> 16) & 1u);
  return (unsigned short)(u >> 16);
}

__device__ __forceinline__ float gelu_fast(float x) {
  float x2 = x * x;
  float p = __builtin_fmaf(0.044715f * x2, x, x);
  float e = __expf(-1.5957691216057308f * p);
  return x / (1.0f + e);
}

__device__ __forceinline__ void gload16(const void* g, void* l) {
  __builtin_amdgcn_global_load_lds((const __attribute__((address_space(1))) void*)g,
                                   (__attribute__((address_space(3))) void*)l,
                                   16, 0, 0);
}

// ---------------- conversion kernels ----------------
__global__ void conv_bf16(const float* __restrict__ in, unsigned short* __restrict__ out, int n4) {
  int i = blockIdx.x * blockDim.x + threadIdx.x;
  if (i >= n4) return;
  float4 v = reinterpret_cast<const float4*>(in)[i];
  ushort4 o;
  o.x = f2bf(v.x); o.y = f2bf(v.y); o.z = f2bf(v.z); o.w = f2bf(v.w);
  reinterpret_cast<ushort4*>(out)[i] = o;
}

__global__ void conv_wdn(const float* __restrict__ in, unsigned short* __restrict__ out) {
  int i = blockIdx.x * blockDim.x + threadIdx.x;
  int idx = i * 4;
  int h = idx & 4095;
  int d = (idx >> 12) & 1023;
  int t = idx >> 22;
  float4 v = *reinterpret_cast<const float4*>(in + (size_t)(t * 1024 + d) * 4096 + h);
  ushort4 o;
  o.x = f2bf(v.x); o.y = f2bf(v.y); o.z = f2bf(v.z); o.w = f2bf(v.w);
  *reinterpret_cast<ushort4*>(out + (size_t)d * 32768 + t * 4096 + h) = o;
}

__global__ void conv_wcls(const float* __restrict__ in, unsigned short* __restrict__ out) {
  int i = blockIdx.x * blockDim.x + threadIdx.x;
  int idx = i * 4;
  int row = idx >> 10;
  float4 v = make_float4(0.f, 0.f, 0.f, 0.f);
  if (row < 1000) v = *reinterpret_cast<const float4*>(in + row * 1024 + (idx & 1023));
  ushort4 o;
  o.x = f2bf(v.x); o.y = f2bf(v.y); o.z = f2bf(v.z); o.w = f2bf(v.w);
  reinterpret_cast<ushort4*>(out)[i] = o;
}

// ---------------- routing ----------------
__global__ void score_init(const float* __restrict__ x, const float* __restrict__ sig,
                           const float* __restrict__ b_down,
                           float* __restrict__ w_ws, float* __restrict__ out_init,
                           float* __restrict__ w_out, float* __restrict__ idx_out) {
  const int b = blockIdx.x;
  const int tid = threadIdx.x;
  const int lane = tid & 63;
  const int wave = tid >> 6;
  const float* xr = x + (size_t)b * 1024;

  float p[8];
  #pragma unroll
  for (int t = 0; t < 8; ++t) p[t] = 0.f;
  for (int k = tid; k < 1024; k += 256) {
    float xv = xr[k];
    #pragma unroll
    for (int t = 0; t < 8; ++t) p[t] += xv * sig[t * 1024 + k];
  }
  #pragma unroll
  for (int t = 0; t < 8; ++t) {
    #pragma unroll
    for (int off = 32; off > 0; off >>= 1) p[t] += __shfl_down(p[t], off);
  }
  __shared__ float red[4][8];
  __shared__ float wsh[8];
  if (lane == 0) {
    #pragma unroll
    for (int t = 0; t < 8; ++t) red[wave][t] = p[t];
  }
  __syncthreads();
  if (tid == 0) {
    float s[8];
    #pragma unroll
    for (int t = 0; t < 8; ++t) s[t] = red[0][t] + red[1][t] + red[2][t] + red[3][t];
    int amax = 0; float mx = s[0];
    #pragma unroll
    for (int t = 1; t < 8; ++t) { if (s[t] > mx) { mx = s[t]; amax = t; } }
    float e[8], sum = 0.f;
    #pragma unroll
    for (int t = 0; t < 8; ++t) { e[t] = expf((s[t] - mx) * 2.0f); sum += e[t]; }
    float inv = 1.0f / sum;
    #pragma unroll
    for (int t = 0; t < 8; ++t) {
      float wv = e[t] * inv;
      wsh[t] = wv;
      w_out[(size_t)b * 8 + t] = wv;
      w_ws[(size_t)b * 8 + t] = wv;
    }
    idx_out[b] = (float)amax;
  }
  __syncthreads();
  for (int d = tid; d < 1024; d += 256) {
    float acc = xr[d];
    #pragma unroll
    for (int t = 0; t < 8; ++t) acc += wsh[t] * b_down[t * 1024 + d];
    out_init[(size_t)b * 1024 + d] = acc;
  }
}

// ---------------- ring-4 pipelined 256x256 GEMM ----------------
// C[m][n] = sum_k A[m][k]*B[n][k], bf16 row-major.
// MODE 0: up (K=1024): Ch = bf16(wcol * gelu(v + bias))
// MODE 1: down split-K (K=8192 per z, z=4): Cf[z] = v
// LDS: A slots 4x16KB @0, B slots 4x16KB @64K. Slot = 256 rows x 64B,
// col-swizzle ((r>>1)&3)<<4 (round-3-proven layout).
template <int MODE>
__global__ __launch_bounds__(512, 2) void gemm8(
    const unsigned short* __restrict__ A, int lda,
    const unsigned short* __restrict__ Bm, int ldb,
    float* __restrict__ Cf,
    unsigned short* __restrict__ Ch,
    const float* __restrict__ bias,
    const float* __restrict__ wcol) {
  constexpr int NU = (MODE == 0) ? 32 : 256;   // K/32 units
  __shared__ char lds[131072];

  const int tid = threadIdx.x;
  const int f = blockIdx.x;
  int m0, n0;
  size_t koff = 0;
  if (MODE == 0) {
    int sf = (f & 7) * 256 + (f >> 3);         // 2048 blocks, 256/XCD
    n0 = (sf >> 4) * 256;
    m0 = (sf & 15) * 256;
  } else {
    int sf = (f & 7) * 32 + (f >> 3);          // 256 blocks, 32/XCD
    int z = sf >> 6, rem = sf & 63;
    m0 = (rem >> 2) * 256;
    n0 = (rem & 3) * 256;
    koff = (size_t)z * 8192;
    Cf += (size_t)z * 4194304;
  }

  // staging (round-3 layout): thread -> row tid/4 (+128 for 2nd gload),
  // col byte (tid&3)*16 inverse-swizzled by ((row>>1)&3)<<4
  const int srow = tid >> 2;
  const int selB = ((tid & 3) << 4) ^ (((tid >> 3) & 3) << 4);
  const unsigned short* Ag = A + (size_t)(m0 + srow) * lda + koff + (selB >> 1);
  const unsigned short* Bg = Bm + (size_t)(n0 + srow) * ldb + koff + (selB >> 1);
  const size_t ldaH = (size_t)128 * lda, ldbH = (size_t)128 * ldb;
  char* const ldsA = lds + tid * 16;
  char* const ldsB = lds + 65536 + tid * 16;

  const int lane = tid & 63;
  const int wave = tid >> 6;
  const int lr = lane & 15, lg = lane >> 4;
  const int wm = (wave >> 2) * 128;            // 2 M-groups x 4 N-groups
  const int wn = (wave & 3) * 64;

  int offA[8], offB[4];
  #pragma unroll
  for (int mi = 0; mi < 8; ++mi) {
    int r = wm + mi * 16 + lr;
    offA[mi] = r * 64 + ((lg << 4) ^ (((r >> 1) & 3) << 4));
  }
  #pragma unroll
  for (int ni = 0; ni < 4; ++ni) {
    int r = wn + ni * 16 + lr;
    offB[ni] = r * 64 + ((lg << 4) ^ (((r >> 1) & 3) << 4));
  }
  const char* const ldsRA = lds;
  const char* const ldsRB = lds + 65536;

  f32x4 acc[8][4];
  #pragma unroll
  for (int i = 0; i < 8; ++i)
    #pragma unroll
    for (int j = 0; j < 4; ++j)
      #pragma unroll
      for (int q = 0; q < 4; ++q) acc[i][j][q] = 0.f;

#define STAGE(u_)                                                        \
  {                                                                      \
    const int s_ = ((u_) & 3) * 16384;                                   \
    const size_t kel_ = (size_t)(u_) * 32;                               \
    gload16(Ag + kel_,        ldsA + s_);                                \
    gload16(Ag + ldaH + kel_, ldsA + s_ + 8192);                         \
    gload16(Bg + kel_,        ldsB + s_);                                \
    gload16(Bg + ldbH + kel_, ldsB + s_ + 8192);                         \
  }

// two phases: {read B0-3+A0-3, (stage u+3), lgkm0, 16 MFMA, BAR},
//             {read A4-7, lgkm0, 16 MFMA}
#define PHASES(u_, doStage)                                              \
  {                                                                      \
    const int s_ = ((u_) & 3) * 16384;                                   \
    bf16x8 av[4], bv[4];                                                 \
    _Pragma("unroll")                                                    \
    for (int ni = 0; ni < 4; ++ni)                                       \
      bv[ni] = *(const bf16x8*)(ldsRB + s_ + offB[ni]);                  \
    _Pragma("unroll")                                                    \
    for (int j = 0; j < 4; ++j)                                          \
      av[j] = *(const bf16x8*)(ldsRA + s_ + offA[j]);                    \
    if (doStage) STAGE((u_) + 3)                                         \
    asm volatile("s_waitcnt lgkmcnt(0)" ::: "memory");                   \
    __builtin_amdgcn_sched_barrier(0);                                   \
    __builtin_amdgcn_s_setprio(1);                                       \
    _Pragma("unroll")                                                    \
    for (int j = 0; j < 4; ++j)                                          \
      _Pragma("unroll")                                                  \
      for (int ni = 0; ni < 4; ++ni)                                     \
        acc[j][ni] = __builtin_amdgcn_mfma_f32_16x16x32_bf16(            \
            av[j], bv[ni], acc[j][ni], 0, 0, 0);                         \
    __builtin_amdgcn_s_setprio(0);                                       \
    __builtin_amdgcn_s_barrier();                                        \
    _Pragma("unroll")                                                    \
    for (int j = 0; j < 4; ++j)                                          \
      av[j] = *(const bf16x8*)(ldsRA + s_ + offA[4 + j]);                \
    asm volatile("s_waitcnt lgkmcnt(0)" ::: "memory");                   \
    __builtin_amdgcn_sched_barrier(0);                                   \
    __builtin_amdgcn_s_setprio(1);                                       \
    _Pragma("unroll")                                                    \
    for (int j = 0; j < 4; ++j)                                          \
      _Pragma("unroll")                                                  \
      for (int ni = 0; ni < 4; ++ni)                                     \
        acc[4 + j][ni] = __builtin_amdgcn_mfma_f32_16x16x32_bf16(        \
            av[j], bv[ni], acc[4 + j][ni], 0, 0, 0);                     \
    __builtin_amdgcn_s_setprio(0);                                       \
  }

  // prologue: 3 units in flight (12 loads)
  STAGE(0) STAGE(1) STAGE(2)

  // main: gate unit u (vmcnt(8) retires stage(u); BAR => all waves' loads
  // landed) BEFORE any ds_read of slot u. Stage(u+3) issued after the BAR.
  #pragma unroll 4
  for (int u = 0; u < NU - 2; ++u) {
    asm volatile("s_waitcnt vmcnt(8)" ::: "memory");
    __builtin_amdgcn_s_barrier();
    PHASES(u, (u < NU - 3))
  }
  // tail: no new stages in flight -> tighten counts
  asm volatile("s_waitcnt vmcnt(4)" ::: "memory");
  __builtin_amdgcn_s_barrier();
  PHASES(NU - 2, false)
  asm volatile("s_waitcnt vmcnt(0)" ::: "memory");
  __builtin_amdgcn_s_barrier();
  PHASES(NU - 1, false)

#undef STAGE
#undef PHASES

  // epilogue: D frag mapping col = lane&15, row = (lane>>4)*4 + r
  #pragma unroll
  for (int mi = 0; mi < 8; ++mi) {
    float wr[4];
    if (MODE == 0) {
      #pragma unroll
      for (int r = 0; r < 4; ++r)
        wr[r] = wcol[(size_t)(m0 + wm + mi * 16 + lg * 4 + r) * 8 + (n0 >> 12)];
    }
    #pragma unroll
    for (int ni = 0; ni < 4; ++ni) {
      int gn = n0 + wn + ni * 16 + lr;
      #pragma unroll
      for (int r = 0; r < 4; ++r) {
        int gm = m0 + wm + mi * 16 + lg * 4 + r;
        float v = acc[mi][ni][r];
        if (MODE == 0) {
          v += bias[gn];
          v = gelu_fast(v) * wr[r];
          Ch[(size_t)gm * 32768 + gn] = f2bf(v);
        } else {
          Cf[(size_t)gm * 1024 + gn] = v;
        }
      }
    }
  }
}

// ---------------- cls GEMM (128-tile, 2-phase; small) ----------------
template <int BN>
__global__ __launch_bounds__(256, 2) void gemm_cls(
    const unsigned short* __restrict__ A, int lda,
    const unsigned short* __restrict__ Bm, int ldb,
    int K, float* __restrict__ Cf, int ldc, int nvalid,
    const float* __restrict__ bias) {
  constexpr int FN = BN / 32;
  __shared__ unsigned short As[128 * 64];
  __shared__ unsigned short Bs[BN * 64];

  const int tid = threadIdx.x;
  const int lane = tid & 63;
  const int wave = tid >> 6;
  const int m0 = blockIdx.y * 128;
  const int n0 = blockIdx.x * BN;
  const int lr = lane & 15;
  const int lg = lane >> 4;
  const int wm = (wave >> 1) * 64;
  const int wn = (wave & 1) * (BN / 2);
  const int sw = (lr & 7) << 4;

  f32x4 acc[4][FN];
  #pragma unroll
  for (int i = 0; i < 4; ++i)
    #pragma unroll
    for (int j = 0; j < FN; ++j)
      #pragma unroll
      for (int q = 0; q < 4; ++q) acc[i][j][q] = 0.f;

  const char* Ab = (const char*)As;
  const char* Bb = (const char*)Bs;
  const int Lw = wave * 1024 + lane * 16;

  for (int k0 = 0; k0 < K; k0 += 64) {
    #pragma unroll
    for (int it = 0; it < 4; ++it) {
      int L = it * 4096 + Lw;
      int row = L >> 7;
      int cb = (L & 127) ^ ((row & 7) << 4);
      gload16(A + (size_t)(m0 + row) * lda + k0 + (cb >> 1),
              (void*)((char*)As + it * 4096 + wave * 1024));
    }
    #pragma unroll
    for (int it = 0; it < FN; ++it) {
      int L = it * 4096 + Lw;
      int row = L >> 7;
      int cb = (L & 127) ^ ((row & 7) << 4);
      gload16(Bm + (size_t)(n0 + row) * ldb + k0 + (cb >> 1),
              (void*)((char*)Bs + it * 4096 + wave * 1024));
    }
    asm volatile("s_waitcnt vmcnt(0)" ::: "memory");
    __syncthreads();

    #pragma unroll
    for (int kk = 0; kk < 2; ++kk) {
      bf16x8 a[4], bfr[FN];
      const int cbase = (kk << 6) + (lg << 4);
      #pragma unroll
      for (int mi = 0; mi < 4; ++mi)
        a[mi] = *(const bf16x8*)(Ab + ((wm + mi * 16 + lr) << 7) + (cbase ^ sw));
      #pragma unroll
      for (int ni = 0; ni < FN; ++ni)
        bfr[ni] = *(const bf16x8*)(Bb + ((wn + ni * 16 + lr) << 7) + (cbase ^ sw));
      #pragma unroll
      for (int mi = 0; mi < 4; ++mi)
        #pragma unroll
        for (int ni = 0; ni < FN; ++ni)
          acc[mi][ni] = __builtin_amdgcn_mfma_f32_16x16x32_bf16(a[mi], bfr[ni], acc[mi][ni], 0, 0, 0);
    }
    __syncthreads();
  }

  #pragma unroll
  for (int mi = 0; mi < 4; ++mi)
    #pragma unroll
    for (int ni = 0; ni < FN; ++ni) {
      int gn = n0 + wn + ni * 16 + lr;
      #pragma unroll
      for (int r = 0; r < 4; ++r) {
        int gm = m0 + wm + mi * 16 + lg * 4 + r;
        if (gn < nvalid) Cf[(size_t)gm * ldc + gn] = acc[mi][ni][r] + bias[gn];
      }
    }
}

// outb = bf16(out_init + p0+p1+p2+p3)
__global__ void combine_k(const float* __restrict__ init, const float* __restrict__ parts,
                          unsigned short* __restrict__ out) {
  int i = blockIdx.x * blockDim.x + threadIdx.x;
  float4 s = reinterpret_cast<const float4*>(init)[i];
  #pragma unroll
  for (int z = 0; z < 4; ++z) {
    float4 p = reinterpret_cast<const float4*>(parts + (size_t)z * 4194304)[i];
    s.x += p.x; s.y += p.y; s.z += p.z; s.w += p.w;
  }
  ushort4 o;
  o.x = f2bf(s.x); o.y = f2bf(s.y); o.z = f2bf(s.z); o.w = f2bf(s.w);
  reinterpret_cast<ushort4*>(out)[i] = o;
}

// ---------------- launch ----------------
extern "C" void kernel_launch(void* const* d_in, const int* in_sizes, int n_in,
                              void* d_out, int out_size, void* d_ws, size_t ws_size,
                              hipStream_t stream) {
  const float* x      = (const float*)d_in[0];
  const float* sig    = (const float*)d_in[1];
  const float* W_up   = (const float*)d_in[2];
  const float* b_up   = (const float*)d_in[3];
  const float* W_down = (const float*)d_in[4];
  const float* b_down = (const float*)d_in[5];
  const float* W_cls  = (const float*)d_in[6];
  const float* b_cls  = (const float*)d_in[7];

  float* outp    = (float*)d_out;
  float* logits  = outp;
  float* idx_out = outp + 4096000;
  float* w_out   = outp + 4096000 + 4096;

  char* ws = (char*)d_ws;
  unsigned short* xb    = (unsigned short*)ws;  ws += 8388608;
  unsigned short* hsc   = (unsigned short*)ws;  ws += 268435456;
  unsigned short* wupb  = (unsigned short*)ws;  ws += 67108864;
  unsigned short* wdnb  = (unsigned short*)ws;  ws += 67108864;
  unsigned short* wclsb = (unsigned short*)ws;  ws += 2097152;
  unsigned short* outb  = (unsigned short*)ws;  ws += 8388608;
  float* out_init       = (float*)ws;           ws += 16777216;
  float* parts          = (float*)ws;           ws += 67108864;
  float* w_ws           = (float*)ws;           ws += 131072;

  dim3 blk(256);

  conv_bf16<<<dim3(4096), blk, 0, stream>>>(x, xb, 1048576);
  score_init<<<dim3(4096), blk, 0, stream>>>(x, sig, b_down, w_ws, out_init, w_out, idx_out);
  conv_bf16<<<dim3(32768), blk, 0, stream>>>(W_up, wupb, 8388608);
  conv_wdn<<<dim3(32768), blk, 0, stream>>>(W_down, wdnb);
  conv_wcls<<<dim3(1024), blk, 0, stream>>>(W_cls, wclsb);

  // up: h_sc = bf16( w * gelu(x @ Wup^T + b_up) ), M=4096 N=32768 K=1024
  gemm8<0><<<dim3(2048), dim3(512), 0, stream>>>(
      xb, 1024, wupb, 1024, (float*)nullptr, hsc, b_up, w_ws);

  // down: parts[z] = h_sc @ Wdn^T (K=32768 split 4)
  gemm8<1><<<dim3(256), dim3(512), 0, stream>>>(
      hsc, 32768, wdnb, 32768, parts, (unsigned short*)nullptr,
      (const float*)nullptr, (const float*)nullptr);

  combine_k<<<dim3(4096), blk, 0, stream>>>(out_init, parts, outb);

  // cls: logits = outb @ Wcls^T + b_cls
  gemm_cls<64><<<dim3(16, 32), blk, 0, stream>>>(
      outb, 1024, wclsb, 1024, 1024, logits, 1000, 1000, b_cls);
}